// Round 1
// baseline (301.024 us; speedup 1.0000x reference)
//
#include <hip/hip_runtime.h>
#include <math.h>

#define NS 480   // n*s
#define NN 16
#define SS 30
#define CC 64
#define HHH 64
#define WW 22
#define PP 7
#define MAXH 22
#define CP 64
#define VV 17
#define DD 1536
#define OC 256
#define SILD 1408   // c*MAXH
#define NTOK 3360   // NS*PP

// ---------------- K1: width pooling (mean + max over w=22) ----------------
__global__ __launch_bounds__(256) void rowpool(const float* __restrict__ sil,
                                               float* __restrict__ rowstat) {
    __shared__ float lds[256 * WW];
    int tid = threadIdx.x;
    long long base = (long long)blockIdx.x * (256 * WW);
    const float4* src = (const float4*)(sil + base);
    float4* dst4 = (float4*)lds;
    for (int i = tid; i < 256 * WW / 4; i += 256) dst4[i] = src[i];
    __syncthreads();
    const float* row = lds + tid * WW;
    float s = 0.f, m = -INFINITY;
    #pragma unroll
    for (int k = 0; k < WW; k++) { float v = row[k]; s += v; m = fmaxf(m, v); }
    float val = s * (1.0f / WW) + m;
    long long R = base / WW + tid;       // R = ((n*CC + c)*SS + s)*HHH + h
    int h = (int)(R % HHH);
    long long t1 = R / HHH;
    int s_i = (int)(t1 % SS);
    long long t2 = t1 / SS;
    int c = (int)(t2 % CC);
    int n = (int)(t2 / CC);
    rowstat[(((long long)(n * SS + s_i)) * CC + c) * HHH + h] = val;
}

// ---------------- K2: build fuse matrix [p][ns][D] ----------------
__global__ __launch_bounds__(256) void fusefill(const float* __restrict__ rowstat,
                                                const float* __restrict__ pose,
                                                const int* __restrict__ min_idx,
                                                float* __restrict__ fuse) {
    long long g = (long long)blockIdx.x * 256 + threadIdx.x;  // < 7*480*1536
    int d = (int)(g % DD);
    long long t = g / DD;
    int nsi = (int)(t % NS);
    int j = (int)(t / NS);
    int n = nsi / SS, s_i = nsi % SS;
    float val;
    if (d < SILD) {
        int c = d / MAXH, hh = d % MAXH;
        int mi = min_idx[j * NN + n];
        val = rowstat[(((long long)nsi) * CC + c) * HHH + mi + hh];
    } else {
        int dd = d - SILD;
        int cpi = dd >> 1, tt = dd & 1;
        const float* pr = pose + (((long long)n * CP + cpi) * SS + s_i) * VV;
        float v;
        if (j == 0) {
            v = (tt == 0) ? (pr[0] + pr[1] + pr[2]) * (1.f / 3.f)
                          : (pr[2] + pr[3] + pr[4]) * (1.f / 3.f);
        } else {
            v = pr[5 + (j - 1) * 2 + tt];
        }
        val = (v > 0.f) ? v : 0.01f * v;
    }
    fuse[g] = val;
}

// ---------------- generic tiled fp32 GEMM: C = A(MxK, lda) * B(KxN row-major) [+ Res] ----------------
__global__ __launch_bounds__(256) void gemm64(
    const float* __restrict__ A, const float* __restrict__ B,
    float* __restrict__ C, const float* __restrict__ Res,
    int M, int N, int K, int lda, int ldc,
    long long aBatch, long long bBatch, long long cBatch)
{
    A += (long long)blockIdx.z * aBatch;
    B += (long long)blockIdx.z * bBatch;
    C += (long long)blockIdx.z * cBatch;
    if (Res) Res += (long long)blockIdx.z * cBatch;
    __shared__ float As[16][68];   // padded: stride 68 keeps 16B align + kills store conflicts
    __shared__ float Bs[16][64];
    int tid = threadIdx.x;
    int row0 = blockIdx.x * 64, col0 = blockIdx.y * 64;
    int tx = tid % 16, ty = tid / 16;
    float acc[4][4] = {};
    for (int k0 = 0; k0 < K; k0 += 16) {
        #pragma unroll
        for (int i = 0; i < 4; i++) {
            int idx = tid + i * 256;
            int ar = idx / 16, ak = idx % 16;
            int grow = row0 + ar;
            float v = 0.f;
            if (grow < M) v = A[(long long)grow * lda + k0 + ak];
            As[ak][ar] = v;
        }
        #pragma unroll
        for (int i = 0; i < 4; i++) {
            int idx = tid + i * 256;
            int bk = idx / 64, bn_ = idx % 64;
            Bs[bk][bn_] = B[(long long)(k0 + bk) * N + col0 + bn_];
        }
        __syncthreads();
        #pragma unroll
        for (int kk = 0; kk < 16; kk++) {
            float4 a4 = *(const float4*)&As[kk][ty * 4];
            float4 b4 = *(const float4*)&Bs[kk][tx * 4];
            float av[4] = {a4.x, a4.y, a4.z, a4.w};
            float bv[4] = {b4.x, b4.y, b4.z, b4.w};
            #pragma unroll
            for (int i = 0; i < 4; i++)
                #pragma unroll
                for (int jj = 0; jj < 4; jj++)
                    acc[i][jj] += av[i] * bv[jj];
        }
        __syncthreads();
    }
    #pragma unroll
    for (int i = 0; i < 4; i++) {
        int grow = row0 + ty * 4 + i;
        if (grow >= M) continue;
        #pragma unroll
        for (int jj = 0; jj < 4; jj++) {
            int gcol = col0 + tx * 4 + jj;
            float v = acc[i][jj];
            if (Res) v += Res[(long long)grow * ldc + gcol];
            C[(long long)grow * ldc + gcol] = v;
        }
    }
}

// ---------------- BatchNorm stats (two-phase, deterministic) ----------------
__global__ __launch_bounds__(256) void bnpartial(const float* __restrict__ x,
                                                 float* __restrict__ partial) {
    int b = blockIdx.x, t = threadIdx.x;
    float s = 0.f, s2 = 0.f;
    for (int r = b * 60; r < b * 60 + 60; r++) {
        float v = x[(long long)r * OC + t];
        s += v; s2 += v * v;
    }
    partial[b * 512 + t] = s;
    partial[b * 512 + 256 + t] = s2;
}

__global__ __launch_bounds__(256) void bnfinal(const float* __restrict__ partial,
                                               const float* __restrict__ gamma,
                                               const float* __restrict__ beta,
                                               float* __restrict__ ssbuf) {
    int t = threadIdx.x;
    float s = 0.f, s2 = 0.f;
    for (int b = 0; b < 56; b++) { s += partial[b * 512 + t]; s2 += partial[b * 512 + 256 + t]; }
    float mu = s / (float)NTOK;
    float var = s2 / (float)NTOK - mu * mu;
    float rsig = rsqrtf(var + 1e-5f);
    float sc = gamma[t] * rsig;
    ssbuf[t] = sc;
    ssbuf[256 + t] = beta[t] - mu * sc;
}

__global__ __launch_bounds__(256) void bnapply(const float* __restrict__ x,
                                               const float* __restrict__ ss,
                                               float* __restrict__ y) {
    long long g = (long long)blockIdx.x * 256 + threadIdx.x;
    int c = threadIdx.x;  // OC==256 and block==256
    y[g] = x[g] * ss[c] + ss[256 + c];
}

// ---------------- attention core per batch-token-group (softmax over HEADS) ----------------
__global__ __launch_bounds__(256) void attn_core(const float* __restrict__ qkv,
                                                 float* __restrict__ ao) {
    __shared__ float q_s[PP * 768];
    __shared__ float a_s[8 * 49];
    int b = blockIdx.x, tid = threadIdx.x;
    const float* src = qkv + (long long)b * PP * 768;
    for (int i = tid; i < PP * 768; i += 256) q_s[i] = src[i];
    __syncthreads();
    for (int t = tid; t < 8 * 49; t += 256) {
        int h_ = t / 49, ij = t % 49, i = ij / 7, j = ij % 7;
        const float* qp = q_s + i * 768 + h_ * 32;
        const float* kp = q_s + j * 768 + 256 + h_ * 32;
        float acc = 0.f;
        #pragma unroll
        for (int d = 0; d < 32; d++) acc += qp[d] * kp[d];
        a_s[t] = acc * 0.17677669529663689f;   // 1/sqrt(32)
    }
    __syncthreads();
    if (tid < 49) {
        float m = -INFINITY;
        #pragma unroll
        for (int h_ = 0; h_ < 8; h_++) m = fmaxf(m, a_s[h_ * 49 + tid]);
        float e[8]; float sum = 0.f;
        #pragma unroll
        for (int h_ = 0; h_ < 8; h_++) { e[h_] = __expf(a_s[h_ * 49 + tid] - m); sum += e[h_]; }
        float inv = 1.f / sum;
        #pragma unroll
        for (int h_ = 0; h_ < 8; h_++) a_s[h_ * 49 + tid] = e[h_] * inv;
    }
    __syncthreads();
    for (int oi = tid; oi < PP * OC; oi += 256) {
        int i = oi / OC, col = oi % OC;
        int h_ = col / 32;
        const float* ap = a_s + h_ * 49 + i * 7;
        const float* vp = q_s + 512 + col;
        float acc = 0.f;
        #pragma unroll
        for (int j = 0; j < 7; j++) acc += ap[j] * vp[j * 768];
        ao[((long long)b * PP + i) * OC + col] = acc;
    }
}

// ---------------- weight transpose: dst[c*rows + r] = src[r*cols + c] ----------------
__global__ __launch_bounds__(256) void transpose_w(const float* __restrict__ src,
                                                   float* __restrict__ dst,
                                                   int rows, int cols) {
    long long g = (long long)blockIdx.x * 256 + threadIdx.x;
    if (g >= (long long)rows * cols) return;
    int r = (int)(g % rows);
    int c = (int)(g / rows);
    dst[g] = src[(long long)r * cols + c];
}

// ---------------- final transpose to [n, C, s, p] ----------------
__global__ __launch_bounds__(256) void out_transpose(const float* __restrict__ xf,
                                                     float* __restrict__ out) {
    long long g = (long long)blockIdx.x * 256 + threadIdx.x; // < 16*256*30*7
    int j = (int)(g % PP);
    long long t = g / PP;
    int s_i = (int)(t % SS);
    long long t2 = t / SS;
    int o = (int)(t2 % OC);
    int n = (int)(t2 / OC);
    out[g] = xf[(((long long)(n * SS + s_i)) * PP + j) * OC + o];
}

extern "C" void kernel_launch(void* const* d_in, const int* in_sizes, int n_in,
                              void* d_out, int out_size, void* d_ws, size_t ws_size,
                              hipStream_t stream) {
    const float* sil   = (const float*)d_in[0];
    const float* pose  = (const float*)d_in[1];
    const float* fcbin = (const float*)d_in[2];
    const float* gamma = (const float*)d_in[3];
    const float* beta  = (const float*)d_in[4];
    const float* wqkv  = (const float*)d_in[5];
    const float* wproj = (const float*)d_in[6];
    const int*   minidx= (const int*)d_in[7];
    float* out = (float*)d_out;

    float* ws = (float*)d_ws;
    float* rowstat = ws;                       // 1,966,080
    float* fuse    = rowstat + 1966080;        // 5,160,960
    float* xraw    = fuse    + 5160960;        // 860,160
    float* partial = xraw    + 860160;         // 28,672
    float* ssbuf   = partial + 28672;          // 512
    float* xbn     = ssbuf   + 512;            // 860,160
    float* wqkvT   = xbn     + 860160;         // 196,608
    float* wprojT  = wqkvT   + 196608;         // 65,536
    float* qkvbuf  = wprojT  + 65536;          // 2,580,480
    float* aobuf   = qkvbuf  + 2580480;        // 860,160
    float* xfin    = aobuf   + 860160;         // 860,160

    rowpool<<<7680, 256, 0, stream>>>(sil, rowstat);
    transpose_w<<<(768 * 256) / 256, 256, 0, stream>>>(wqkv, wqkvT, 768, 256);
    transpose_w<<<(256 * 256) / 256, 256, 0, stream>>>(wproj, wprojT, 256, 256);
    fusefill<<<20160, 256, 0, stream>>>(rowstat, pose, minidx, fuse);
    gemm64<<<dim3(8, 4, 7), 256, 0, stream>>>(fuse, fcbin, xraw, nullptr,
        480, 256, 1536, 1536, 1792, (long long)480 * 1536, (long long)1536 * 256, 256);
    bnpartial<<<56, 256, 0, stream>>>(xraw, partial);
    bnfinal<<<1, 256, 0, stream>>>(partial, gamma, beta, ssbuf);
    bnapply<<<3360, 256, 0, stream>>>(xraw, ssbuf, xbn);
    gemm64<<<dim3(53, 12, 1), 256, 0, stream>>>(xbn, wqkvT, qkvbuf, nullptr,
        3360, 768, 256, 256, 768, 0, 0, 0);
    attn_core<<<480, 256, 0, stream>>>(qkvbuf, aobuf);
    gemm64<<<dim3(53, 4, 1), 256, 0, stream>>>(aobuf, wprojT, xfin, xbn,
        3360, 256, 256, 256, 256, 0, 0, 0);
    out_transpose<<<3360, 256, 0, stream>>>(xfin, out);
}

// Round 2
// 135.452 us; speedup vs baseline: 2.2224x; 2.2224x over previous
//
#include <hip/hip_runtime.h>
#include <hip/hip_bf16.h>
#include <math.h>

#define NS 480   // n*s
#define NN 16
#define SS 30
#define CC 64
#define HHH 64
#define WW 22
#define PP 7
#define MAXH 22
#define CP 64
#define VV 17
#define DD 1536
#define OC 256
#define SILD 1408   // c*MAXH
#define NTOK 3360   // NS*PP

typedef __bf16 bf16x8 __attribute__((ext_vector_type(8)));
typedef float f32x4 __attribute__((ext_vector_type(4)));
typedef short short8 __attribute__((ext_vector_type(8)));

// ---------------- K1: width pooling (mean + max over w=22) ----------------
__global__ __launch_bounds__(256) void rowpool(const float* __restrict__ sil,
                                               float* __restrict__ rowstat) {
    __shared__ float lds[256 * WW];
    int tid = threadIdx.x;
    long long base = (long long)blockIdx.x * (256 * WW);
    const float4* src = (const float4*)(sil + base);
    float4* dst4 = (float4*)lds;
    for (int i = tid; i < 256 * WW / 4; i += 256) dst4[i] = src[i];
    __syncthreads();
    const float* row = lds + tid * WW;
    float s = 0.f, m = -INFINITY;
    #pragma unroll
    for (int k = 0; k < WW; k++) { float v = row[k]; s += v; m = fmaxf(m, v); }
    float val = s * (1.0f / WW) + m;
    long long R = base / WW + tid;       // R = ((n*CC + c)*SS + s)*HHH + h
    int h = (int)(R % HHH);
    long long t1 = R / HHH;
    int s_i = (int)(t1 % SS);
    long long t2 = t1 / SS;
    int c = (int)(t2 % CC);
    int n = (int)(t2 / CC);
    rowstat[(((long long)(n * SS + s_i)) * CC + c) * HHH + h] = val;
}

// ---------------- K2: build fuse matrix [p][ns][D] in bf16 ----------------
__global__ __launch_bounds__(256) void fusefill(const float* __restrict__ rowstat,
                                                const float* __restrict__ pose,
                                                const int* __restrict__ min_idx,
                                                __hip_bfloat16* __restrict__ fuse) {
    long long g = (long long)blockIdx.x * 256 + threadIdx.x;  // < 7*480*1536
    int d = (int)(g % DD);
    long long t = g / DD;
    int nsi = (int)(t % NS);
    int j = (int)(t / NS);
    int n = nsi / SS, s_i = nsi % SS;
    float val;
    if (d < SILD) {
        int c = d / MAXH, hh = d % MAXH;
        int mi = min_idx[j * NN + n];
        val = rowstat[(((long long)nsi) * CC + c) * HHH + mi + hh];
    } else {
        int dd = d - SILD;
        int cpi = dd >> 1, tt = dd & 1;
        const float* pr = pose + (((long long)n * CP + cpi) * SS + s_i) * VV;
        float v;
        if (j == 0) {
            v = (tt == 0) ? (pr[0] + pr[1] + pr[2]) * (1.f / 3.f)
                          : (pr[2] + pr[3] + pr[4]) * (1.f / 3.f);
        } else {
            v = pr[5 + (j - 1) * 2 + tt];
        }
        val = (v > 0.f) ? v : 0.01f * v;
    }
    fuse[g] = __float2bfloat16(val);
}

// ---------------- weight fp32 -> bf16 copy (layout preserved) ----------------
__global__ __launch_bounds__(256) void cvt_bf16(const float* __restrict__ src,
                                                __hip_bfloat16* __restrict__ dst,
                                                int nelem) {
    int g = blockIdx.x * 256 + threadIdx.x;
    if (g < nelem) dst[g] = __float2bfloat16(src[g]);
}

// ---------------- fc_bin [p][D][OC] fp32 -> [p][OC][D] bf16 ----------------
__global__ __launch_bounds__(256) void fcbin_tc(const float* __restrict__ src,
                                                __hip_bfloat16* __restrict__ dst) {
    __shared__ float t[64][65];
    int p = blockIdx.z, dt = blockIdx.x, ot = blockIdx.y;
    const float* s = src + ((long long)p * DD + dt * 64) * OC + ot * 64;
    for (int i = threadIdx.x; i < 64 * 64; i += 256) {
        int r = i >> 6, c = i & 63;
        t[r][c] = s[(long long)r * OC + c];
    }
    __syncthreads();
    __hip_bfloat16* d = dst + ((long long)p * OC + ot * 64) * DD + dt * 64;
    for (int i = threadIdx.x; i < 64 * 64; i += 256) {
        int r = i >> 6, c = i & 63;   // r = oc index, c = d index
        d[(long long)r * DD + c] = __float2bfloat16(t[c][r]);
    }
}

// ---------------- bf16 MFMA GEMM: C = A(MxK bf16) * Bt(NxK bf16)^T [+ Res] ----------------
// 64x64 block tile, 4 waves of 32x32, BK=64, XOR-swizzled LDS.
__global__ __launch_bounds__(256) void gemm_mfma(
    const __hip_bfloat16* __restrict__ A, const __hip_bfloat16* __restrict__ Bt,
    float* __restrict__ C, const float* __restrict__ Res,
    int M, int N, int K, int lda, int ldc,
    long long aBatch, long long bBatch, long long cBatch)
{
    A  += (long long)blockIdx.z * aBatch;
    Bt += (long long)blockIdx.z * bBatch;
    C  += (long long)blockIdx.z * cBatch;
    const float* R = Res ? (Res + (long long)blockIdx.z * cBatch) : nullptr;

    __shared__ short As[64 * 64];
    __shared__ short Bs[64 * 64];
    int tid = threadIdx.x;
    int lane = tid & 63, w = tid >> 6;
    int wm = w >> 1, wn = w & 1;
    int row0 = blockIdx.x * 64, col0 = blockIdx.y * 64;

    f32x4 acc[2][2] = {};

    for (int k0 = 0; k0 < K; k0 += 64) {
        #pragma unroll
        for (int i = 0; i < 2; i++) {
            int idx = tid + i * 256;          // 0..511
            int r = idx >> 3, c = idx & 7;
            short8 v = {};
            int grow = row0 + r;
            if (grow < M) v = *(const short8*)(const void*)(A + (long long)grow * lda + k0 + c * 8);
            *(short8*)&As[r * 64 + ((c ^ (r & 7)) << 3)] = v;
        }
        #pragma unroll
        for (int i = 0; i < 2; i++) {
            int idx = tid + i * 256;
            int r = idx >> 3, c = idx & 7;
            short8 v = {};
            int gcol = col0 + r;
            if (gcol < N) v = *(const short8*)(const void*)(Bt + (long long)gcol * K + k0 + c * 8);
            *(short8*)&Bs[r * 64 + ((c ^ (r & 7)) << 3)] = v;
        }
        __syncthreads();
        #pragma unroll
        for (int ks = 0; ks < 2; ks++) {
            bf16x8 af[2], bfr[2];
            #pragma unroll
            for (int f = 0; f < 2; f++) {
                int r  = wm * 32 + f * 16 + (lane & 15);
                int ca = (ks * 4 + (lane >> 4)) ^ (r & 7);
                af[f] = *(const bf16x8*)&As[r * 64 + (ca << 3)];
                int rb = wn * 32 + f * 16 + (lane & 15);
                int cb = (ks * 4 + (lane >> 4)) ^ (rb & 7);
                bfr[f] = *(const bf16x8*)&Bs[rb * 64 + (cb << 3)];
            }
            #pragma unroll
            for (int fm = 0; fm < 2; fm++)
                #pragma unroll
                for (int fn = 0; fn < 2; fn++)
                    acc[fm][fn] = __builtin_amdgcn_mfma_f32_16x16x32_bf16(
                        af[fm], bfr[fn], acc[fm][fn], 0, 0, 0);
        }
        __syncthreads();
    }
    #pragma unroll
    for (int fm = 0; fm < 2; fm++) {
        #pragma unroll
        for (int fn = 0; fn < 2; fn++) {
            #pragma unroll
            for (int r4 = 0; r4 < 4; r4++) {
                int grow = row0 + wm * 32 + fm * 16 + (lane >> 4) * 4 + r4;
                int gcol = col0 + wn * 32 + fn * 16 + (lane & 15);
                if (grow < M && gcol < N) {
                    float v = acc[fm][fn][r4];
                    if (R) v += R[(long long)grow * ldc + gcol];
                    C[(long long)grow * ldc + gcol] = v;
                }
            }
        }
    }
}

// ---------------- BatchNorm stats (two-phase, deterministic) ----------------
__global__ __launch_bounds__(256) void bnpartial(const float* __restrict__ x,
                                                 float* __restrict__ partial) {
    int b = blockIdx.x, t = threadIdx.x;
    float s = 0.f, s2 = 0.f;
    for (int r = b * 60; r < b * 60 + 60; r++) {
        float v = x[(long long)r * OC + t];
        s += v; s2 += v * v;
    }
    partial[b * 512 + t] = s;
    partial[b * 512 + 256 + t] = s2;
}

__global__ __launch_bounds__(256) void bnfinal(const float* __restrict__ partial,
                                               const float* __restrict__ gamma,
                                               const float* __restrict__ beta,
                                               float* __restrict__ ssbuf) {
    int t = threadIdx.x;
    float s = 0.f, s2 = 0.f;
    for (int b = 0; b < 56; b++) { s += partial[b * 512 + t]; s2 += partial[b * 512 + 256 + t]; }
    float mu = s / (float)NTOK;
    float var = s2 / (float)NTOK - mu * mu;
    float rsig = rsqrtf(var + 1e-5f);
    float sc = gamma[t] * rsig;
    ssbuf[t] = sc;
    ssbuf[256 + t] = beta[t] - mu * sc;
}

__global__ __launch_bounds__(256) void bnapply(const float* __restrict__ x,
                                               const float* __restrict__ ss,
                                               float* __restrict__ y,
                                               __hip_bfloat16* __restrict__ y16) {
    long long g = (long long)blockIdx.x * 256 + threadIdx.x;
    int c = threadIdx.x;  // OC==256 and block==256
    float v = x[g] * ss[c] + ss[256 + c];
    y[g] = v;
    y16[g] = __float2bfloat16(v);
}

// ---------------- attention core (softmax over HEADS) ----------------
__global__ __launch_bounds__(256) void attn_core(const float* __restrict__ qkv,
                                                 __hip_bfloat16* __restrict__ ao) {
    __shared__ float q_s[PP * 768];
    __shared__ float a_s[8 * 49];
    int b = blockIdx.x, tid = threadIdx.x;
    const float* src = qkv + (long long)b * PP * 768;
    for (int i = tid; i < PP * 768; i += 256) q_s[i] = src[i];
    __syncthreads();
    for (int t = tid; t < 8 * 49; t += 256) {
        int h_ = t / 49, ij = t % 49, i = ij / 7, j = ij % 7;
        const float* qp = q_s + i * 768 + h_ * 32;
        const float* kp = q_s + j * 768 + 256 + h_ * 32;
        float acc = 0.f;
        #pragma unroll
        for (int d = 0; d < 32; d++) acc += qp[d] * kp[d];
        a_s[t] = acc * 0.17677669529663689f;   // 1/sqrt(32)
    }
    __syncthreads();
    if (tid < 49) {
        float m = -INFINITY;
        #pragma unroll
        for (int h_ = 0; h_ < 8; h_++) m = fmaxf(m, a_s[h_ * 49 + tid]);
        float e[8]; float sum = 0.f;
        #pragma unroll
        for (int h_ = 0; h_ < 8; h_++) { e[h_] = __expf(a_s[h_ * 49 + tid] - m); sum += e[h_]; }
        float inv = 1.f / sum;
        #pragma unroll
        for (int h_ = 0; h_ < 8; h_++) a_s[h_ * 49 + tid] = e[h_] * inv;
    }
    __syncthreads();
    for (int oi = tid; oi < PP * OC; oi += 256) {
        int i = oi / OC, col = oi % OC;
        int h_ = col / 32;
        const float* ap = a_s + h_ * 49 + i * 7;
        const float* vp = q_s + 512 + col;
        float acc = 0.f;
        #pragma unroll
        for (int j = 0; j < 7; j++) acc += ap[j] * vp[j * 768];
        ao[((long long)b * PP + i) * OC + col] = __float2bfloat16(acc);
    }
}

// ---------------- final transpose to [n, C, s, p] ----------------
__global__ __launch_bounds__(256) void out_transpose(const float* __restrict__ xf,
                                                     float* __restrict__ out) {
    long long g = (long long)blockIdx.x * 256 + threadIdx.x; // < 16*256*30*7
    int j = (int)(g % PP);
    long long t = g / PP;
    int s_i = (int)(t % SS);
    long long t2 = t / SS;
    int o = (int)(t2 % OC);
    int n = (int)(t2 / OC);
    out[g] = xf[(((long long)(n * SS + s_i)) * PP + j) * OC + o];
}

extern "C" void kernel_launch(void* const* d_in, const int* in_sizes, int n_in,
                              void* d_out, int out_size, void* d_ws, size_t ws_size,
                              hipStream_t stream) {
    const float* sil   = (const float*)d_in[0];
    const float* pose  = (const float*)d_in[1];
    const float* fcbin = (const float*)d_in[2];
    const float* gamma = (const float*)d_in[3];
    const float* beta  = (const float*)d_in[4];
    const float* wqkv  = (const float*)d_in[5];
    const float* wproj = (const float*)d_in[6];
    const int*   minidx= (const int*)d_in[7];
    float* out = (float*)d_out;

    float* ws = (float*)d_ws;
    float* rowstat = ws;                                        // 1,966,080 f32
    __hip_bfloat16* fuse16   = (__hip_bfloat16*)(ws + 1966080); // 5,160,960 bf16
    float* xraw    = ws + 4546560;                              // 860,160 f32 ([ns][7][256])
    float* partial = ws + 5406720;                              // 28,672
    float* ssbuf   = ws + 5435392;                              // 512
    float* xbn     = ws + 5435904;                              // 860,160
    __hip_bfloat16* xbn16    = (__hip_bfloat16*)(ws + 6296064); // 860,160 bf16
    __hip_bfloat16* wqkv16   = (__hip_bfloat16*)(ws + 6726144); // 196,608 bf16
    __hip_bfloat16* wproj16  = (__hip_bfloat16*)(ws + 6824448); // 65,536 bf16
    __hip_bfloat16* fcbinT16 = (__hip_bfloat16*)(ws + 6857216); // 2,752,512 bf16
    float* qkvbuf  = ws + 8233472;                              // 2,580,480
    __hip_bfloat16* ao16     = (__hip_bfloat16*)(ws + 10813952);// 860,160 bf16
    float* xfin    = ws + 11244032;                             // 860,160

    rowpool<<<7680, 256, 0, stream>>>(sil, rowstat);
    cvt_bf16<<<768, 256, 0, stream>>>(wqkv, wqkv16, 196608);
    cvt_bf16<<<256, 256, 0, stream>>>(wproj, wproj16, 65536);
    fcbin_tc<<<dim3(24, 4, 7), 256, 0, stream>>>(fcbin, fcbinT16);
    fusefill<<<20160, 256, 0, stream>>>(rowstat, pose, minidx, fuse16);
    // fc: per-part [480 x 1536] * [1536 x 256] -> xraw rows interleaved [ns][p][256]
    gemm_mfma<<<dim3(8, 4, 7), 256, 0, stream>>>(fuse16, fcbinT16, xraw, nullptr,
        480, 256, 1536, 1536, 1792, (long long)480 * 1536, (long long)256 * 1536, 256);
    bnpartial<<<56, 256, 0, stream>>>(xraw, partial);
    bnfinal<<<1, 256, 0, stream>>>(partial, gamma, beta, ssbuf);
    bnapply<<<3360, 256, 0, stream>>>(xraw, ssbuf, xbn, xbn16);
    // qkv: [3360 x 256] * [256 x 768]
    gemm_mfma<<<dim3(53, 12, 1), 256, 0, stream>>>(xbn16, wqkv16, qkvbuf, nullptr,
        3360, 768, 256, 256, 768, 0, 0, 0);
    attn_core<<<480, 256, 0, stream>>>(qkvbuf, ao16);
    // proj + residual: [3360 x 256] * [256 x 256] + xbn
    gemm_mfma<<<dim3(53, 4, 1), 256, 0, stream>>>(ao16, wproj16, xfin, xbn,
        3360, 256, 256, 256, 256, 0, 0, 0);
    out_transpose<<<3360, 256, 0, stream>>>(xfin, out);
}

// Round 3
// 95.957 us; speedup vs baseline: 3.1371x; 1.4116x over previous
//
#include <hip/hip_runtime.h>
#include <hip/hip_bf16.h>
#include <math.h>

#define NS 480   // n*s
#define NN 16
#define SS 30
#define CC 64
#define HHH 64
#define WW 22
#define PP 7
#define MAXH 22
#define CP 64
#define VV 17
#define DD 1536
#define OC 256
#define SILD 1408   // c*MAXH
#define NTOK 3360   // NS*PP

typedef __bf16 bf16x8 __attribute__((ext_vector_type(8)));
typedef float f32x4 __attribute__((ext_vector_type(4)));
typedef short short8 __attribute__((ext_vector_type(8)));

__device__ __forceinline__ void gl_lds16(const void* g, void* l) {
    __builtin_amdgcn_global_load_lds(
        (const __attribute__((address_space(1))) void*)g,
        (__attribute__((address_space(3))) void*)l, 16, 0, 0);
}

// ---------------- K1: width pooling (mean + max over w=22) ----------------
__global__ __launch_bounds__(256) void rowpool(const float* __restrict__ sil,
                                               float* __restrict__ rowstat) {
    __shared__ float lds[256 * WW];
    int tid = threadIdx.x;
    long long base = (long long)blockIdx.x * (256 * WW);
    const float4* src = (const float4*)(sil + base);
    float4* dst4 = (float4*)lds;
    for (int i = tid; i < 256 * WW / 4; i += 256) dst4[i] = src[i];
    __syncthreads();
    const float* row = lds + tid * WW;
    float s = 0.f, m = -INFINITY;
    #pragma unroll
    for (int k = 0; k < WW; k++) { float v = row[k]; s += v; m = fmaxf(m, v); }
    float val = s * (1.0f / WW) + m;
    long long R = base / WW + tid;       // R = ((n*CC + c)*SS + s)*HHH + h
    int h = (int)(R % HHH);
    long long t1 = R / HHH;
    int s_i = (int)(t1 % SS);
    long long t2 = t1 / SS;
    int c = (int)(t2 % CC);
    int n = (int)(t2 / CC);
    rowstat[(((long long)(n * SS + s_i)) * CC + c) * HHH + h] = val;
}

// ---------------- K2: build fuse matrix [p][ns][D] in bf16 ----------------
__global__ __launch_bounds__(256) void fusefill(const float* __restrict__ rowstat,
                                                const float* __restrict__ pose,
                                                const int* __restrict__ min_idx,
                                                __hip_bfloat16* __restrict__ fuse) {
    long long g = (long long)blockIdx.x * 256 + threadIdx.x;  // < 7*480*1536
    int d = (int)(g % DD);
    long long t = g / DD;
    int nsi = (int)(t % NS);
    int j = (int)(t / NS);
    int n = nsi / SS, s_i = nsi % SS;
    float val;
    if (d < SILD) {
        int c = d / MAXH, hh = d % MAXH;
        int mi = min_idx[j * NN + n];
        val = rowstat[(((long long)nsi) * CC + c) * HHH + mi + hh];
    } else {
        int dd = d - SILD;
        int cpi = dd >> 1, tt = dd & 1;
        const float* pr = pose + (((long long)n * CP + cpi) * SS + s_i) * VV;
        float v;
        if (j == 0) {
            v = (tt == 0) ? (pr[0] + pr[1] + pr[2]) * (1.f / 3.f)
                          : (pr[2] + pr[3] + pr[4]) * (1.f / 3.f);
        } else {
            v = pr[5 + (j - 1) * 2 + tt];
        }
        val = (v > 0.f) ? v : 0.01f * v;
    }
    fuse[g] = __float2bfloat16(val);
}

// ---------------- merged weight prep: cvt wqkv, cvt wproj, fcbin transpose ----------------
__global__ __launch_bounds__(256) void weightprep(const float* __restrict__ wqkv,
                                                  const float* __restrict__ wproj,
                                                  const float* __restrict__ fcbin,
                                                  __hip_bfloat16* __restrict__ wqkv16,
                                                  __hip_bfloat16* __restrict__ wproj16,
                                                  __hip_bfloat16* __restrict__ fcbinT16) {
    int b = blockIdx.x;
    if (b < 768) { int g = b * 256 + threadIdx.x; wqkv16[g] = __float2bfloat16(wqkv[g]); return; }
    if (b < 1024) { int g = (b - 768) * 256 + threadIdx.x; wproj16[g] = __float2bfloat16(wproj[g]); return; }
    __shared__ float t[64][65];
    int bb = b - 1024;                 // 0..671
    int p = bb / 96, r2 = bb % 96, dt = r2 / 4, ot = r2 % 4;
    const float* s = fcbin + ((long long)p * DD + dt * 64) * OC + ot * 64;
    for (int i = threadIdx.x; i < 64 * 64; i += 256) {
        int r = i >> 6, c = i & 63;
        t[r][c] = s[(long long)r * OC + c];
    }
    __syncthreads();
    __hip_bfloat16* d = fcbinT16 + ((long long)p * OC + ot * 64) * DD + dt * 64;
    for (int i = threadIdx.x; i < 64 * 64; i += 256) {
        int r = i >> 6, c = i & 63;
        d[(long long)r * DD + c] = __float2bfloat16(t[c][r]);
    }
}

// ---------------- unified MFMA GEMM, 64x64 tile, 2-phase dbuf, gload_lds ----------------
// ABF16: A is bf16 (global_load_lds); else A is f32 xraw with BN applied on stage.
// EPI 0: C=xraw + BN column partials.  EPI 1: plain C.  EPI 2: residual(BN(xraw)) + transposed out.
template<bool ABF16, int EPI>
__global__ __launch_bounds__(256) void gemm2(
    const void* __restrict__ Ain, const __hip_bfloat16* __restrict__ Bt,
    float* __restrict__ Cf, float* __restrict__ outp,
    const float* __restrict__ xres, float* __restrict__ partial,
    const float* __restrict__ ssb,
    int M, int N, int K, int lda, int ldc,
    long long aBatch, long long bBatch, long long cBatch)
{
    const __hip_bfloat16* Ab = (const __hip_bfloat16*)Ain + (ABF16 ? (long long)blockIdx.z * aBatch : 0);
    const float* Af = (const float*)Ain;
    const __hip_bfloat16* Bq = Bt + (long long)blockIdx.z * bBatch;
    float* C = Cf ? (Cf + (long long)blockIdx.z * cBatch) : nullptr;

    __shared__ short As[2][4096];
    __shared__ short Bs[2][4096];
    __shared__ float red[4][2][16][2];
    __shared__ float ssl[512];
    __shared__ float Ct[(EPI == 2) ? 64 * 65 : 1];

    int tid = threadIdx.x, lane = tid & 63, w = tid >> 6;
    int wm = w >> 1, wn = w & 1;
    int row0 = blockIdx.x * 64, col0 = blockIdx.y * 64;

    if (!ABF16 || EPI == 2) {
        for (int i = tid; i < 512; i += 256) ssl[i] = ssb[i];
        if (!ABF16) __syncthreads();
    }

    f32x4 acc[2][2] = {};
    int nt = K >> 6;

    auto stageB = [&](int buf, int k0) {
        int cc = lane & 7;
        #pragma unroll
        for (int i = 0; i < 2; i++) {
            int r = w * 16 + i * 8 + (lane >> 3);
            int gcol = col0 + r; if (gcol >= N) gcol = N - 1;
            const char* g = (const char*)Bq + (((long long)gcol * K + k0) << 1) + ((cc ^ (r & 7)) << 4);
            gl_lds16(g, (char*)&Bs[buf][0] + (w * 16 + i * 8) * 128);
        }
    };
    auto stageA = [&](int buf, int k0) {
        if constexpr (ABF16) {
            int cc = lane & 7;
            #pragma unroll
            for (int i = 0; i < 2; i++) {
                int r = w * 16 + i * 8 + (lane >> 3);
                int grow = row0 + r; if (grow >= M) grow = M - 1;
                const char* g = (const char*)Ab + (((long long)grow * lda + k0) << 1) + ((cc ^ (r & 7)) << 4);
                gl_lds16(g, (char*)&As[buf][0] + (w * 16 + i * 8) * 128);
            }
        } else {
            #pragma unroll
            for (int i = 0; i < 2; i++) {
                int id = tid + i * 256;          // 0..511
                int r = id >> 3, c8 = id & 7;
                int grow = row0 + r; if (grow >= M) grow = M - 1;
                const float* src = Af + (long long)grow * lda + k0 + c8 * 8;
                float4 v0 = *(const float4*)src;
                float4 v1 = *(const float4*)(src + 4);
                int kb = k0 + c8 * 8;
                float vv[8] = {v0.x, v0.y, v0.z, v0.w, v1.x, v1.y, v1.z, v1.w};
                short8 o;
                #pragma unroll
                for (int j = 0; j < 8; j++) {
                    float tv = vv[j] * ssl[kb + j] + ssl[256 + kb + j];
                    union { __hip_bfloat16 h; short s; } u; u.h = __float2bfloat16(tv);
                    o[j] = u.s;
                }
                *(short8*)((char*)&As[buf][0] + r * 128 + ((c8 ^ (r & 7)) << 4)) = o;
            }
        }
    };

    stageA(0, 0); stageB(0, 0);
    __syncthreads();
    for (int t = 0; t < nt; t++) {
        int cur = t & 1;
        if (t + 1 < nt) { stageA(cur ^ 1, (t + 1) << 6); stageB(cur ^ 1, (t + 1) << 6); }
        #pragma unroll
        for (int ks = 0; ks < 2; ks++) {
            bf16x8 af[2], bfv[2];
            #pragma unroll
            for (int f = 0; f < 2; f++) {
                int r = wm * 32 + f * 16 + (lane & 15);
                int ca = (ks * 4 + (lane >> 4)) ^ (r & 7);
                af[f] = *(const bf16x8*)((const char*)&As[cur][0] + r * 128 + (ca << 4));
                int rb = wn * 32 + f * 16 + (lane & 15);
                int cb = (ks * 4 + (lane >> 4)) ^ (rb & 7);
                bfv[f] = *(const bf16x8*)((const char*)&Bs[cur][0] + rb * 128 + (cb << 4));
            }
            #pragma unroll
            for (int fm = 0; fm < 2; fm++)
                #pragma unroll
                for (int fn = 0; fn < 2; fn++)
                    acc[fm][fn] = __builtin_amdgcn_mfma_f32_16x16x32_bf16(
                        af[fm], bfv[fn], acc[fm][fn], 0, 0, 0);
        }
        __syncthreads();
    }

    if constexpr (EPI == 0) {
        float s[2] = {0.f, 0.f}, s2[2] = {0.f, 0.f};
        #pragma unroll
        for (int fm = 0; fm < 2; fm++) {
            #pragma unroll
            for (int fn = 0; fn < 2; fn++) {
                #pragma unroll
                for (int r4 = 0; r4 < 4; r4++) {
                    int grow = row0 + wm * 32 + fm * 16 + (lane >> 4) * 4 + r4;
                    int gcol = col0 + wn * 32 + fn * 16 + (lane & 15);
                    if (grow < M) {
                        float v = acc[fm][fn][r4];
                        C[(long long)grow * ldc + gcol] = v;
                        s[fn] += v; s2[fn] += v * v;
                    }
                }
            }
        }
        #pragma unroll
        for (int off = 16; off < 64; off <<= 1) {
            s[0] += __shfl_xor(s[0], off);  s2[0] += __shfl_xor(s2[0], off);
            s[1] += __shfl_xor(s[1], off);  s2[1] += __shfl_xor(s2[1], off);
        }
        if (lane < 16) {
            red[w][0][lane][0] = s[0]; red[w][0][lane][1] = s2[0];
            red[w][1][lane][0] = s[1]; red[w][1][lane][1] = s2[1];
        }
        __syncthreads();
        if (tid < 128) {
            int col = tid >> 1, which = tid & 1;
            int wn2 = (col >> 5) & 1, fn2 = (col >> 4) & 1, c16 = col & 15;
            float v = red[wn2 * 1 + 0 + (0) + (wn2)][fn2][c16][which]; // placeholder avoided below
            v = red[wn2][fn2][c16][which] + red[2 + wn2][fn2][c16][which];
            partial[((long long)(blockIdx.z * 8 + blockIdx.x) * 2 + which) * 256 + blockIdx.y * 64 + col] = v;
        }
    } else if constexpr (EPI == 1) {
        #pragma unroll
        for (int fm = 0; fm < 2; fm++)
            #pragma unroll
            for (int fn = 0; fn < 2; fn++)
                #pragma unroll
                for (int r4 = 0; r4 < 4; r4++) {
                    int grow = row0 + wm * 32 + fm * 16 + (lane >> 4) * 4 + r4;
                    int gcol = col0 + wn * 32 + fn * 16 + (lane & 15);
                    if (grow < M) C[(long long)grow * ldc + gcol] = acc[fm][fn][r4];
                }
    } else {
        // EPI == 2: residual = BN(xraw), transpose through LDS, coalesced out write
        #pragma unroll
        for (int fm = 0; fm < 2; fm++)
            #pragma unroll
            for (int fn = 0; fn < 2; fn++)
                #pragma unroll
                for (int r4 = 0; r4 < 4; r4++) {
                    int rl = wm * 32 + fm * 16 + (lane >> 4) * 4 + r4;
                    int cl = wn * 32 + fn * 16 + (lane & 15);
                    int tr = row0 + rl;
                    if (tr < M) {
                        int o = col0 + cl;
                        float x = xres[(long long)tr * 256 + o];
                        Ct[cl * 65 + rl] = acc[fm][fn][r4] + x * ssl[o] + ssl[256 + o];
                    }
                }
        __syncthreads();
        int ol = tid >> 2, g4 = tid & 3;
        int o = col0 + ol;
        #pragma unroll
        for (int i = 0; i < 16; i++) {
            int tl = g4 * 16 + i;
            int tr = row0 + tl;
            if (tr < M) {
                int n = tr / 210;
                int rem = tr - n * 210;
                outp[((long long)(n * 256 + o)) * 210 + rem] = Ct[ol * 65 + tl];
            }
        }
    }
}

// ---------------- BN final: partials -> scale/shift ----------------
__global__ __launch_bounds__(256) void bnfinal(const float* __restrict__ partial,
                                               const float* __restrict__ gamma,
                                               const float* __restrict__ beta,
                                               float* __restrict__ ssbuf) {
    int t = threadIdx.x;
    float s = 0.f, s2 = 0.f;
    for (int b = 0; b < 56; b++) { s += partial[b * 512 + t]; s2 += partial[b * 512 + 256 + t]; }
    float mu = s / (float)NTOK;
    float var = s2 / (float)NTOK - mu * mu;
    float rsig = rsqrtf(var + 1e-5f);
    float sc = gamma[t] * rsig;
    ssbuf[t] = sc;
    ssbuf[256 + t] = beta[t] - mu * sc;
}

// ---------------- attention core (softmax over HEADS) ----------------
__global__ __launch_bounds__(256) void attn_core(const float* __restrict__ qkv,
                                                 __hip_bfloat16* __restrict__ ao) {
    __shared__ float q_s[PP * 768];
    __shared__ float a_s[8 * 49];
    int b = blockIdx.x, tid = threadIdx.x;
    const float* src = qkv + (long long)b * PP * 768;
    for (int i = tid; i < PP * 768; i += 256) q_s[i] = src[i];
    __syncthreads();
    for (int t = tid; t < 8 * 49; t += 256) {
        int h_ = t / 49, ij = t % 49, i = ij / 7, j = ij % 7;
        const float* qp = q_s + i * 768 + h_ * 32;
        const float* kp = q_s + j * 768 + 256 + h_ * 32;
        float acc = 0.f;
        #pragma unroll
        for (int d = 0; d < 32; d++) acc += qp[d] * kp[d];
        a_s[t] = acc * 0.17677669529663689f;   // 1/sqrt(32)
    }
    __syncthreads();
    if (tid < 49) {
        float m = -INFINITY;
        #pragma unroll
        for (int h_ = 0; h_ < 8; h_++) m = fmaxf(m, a_s[h_ * 49 + tid]);
        float e[8]; float sum = 0.f;
        #pragma unroll
        for (int h_ = 0; h_ < 8; h_++) { e[h_] = __expf(a_s[h_ * 49 + tid] - m); sum += e[h_]; }
        float inv = 1.f / sum;
        #pragma unroll
        for (int h_ = 0; h_ < 8; h_++) a_s[h_ * 49 + tid] = e[h_] * inv;
    }
    __syncthreads();
    for (int oi = tid; oi < PP * OC; oi += 256) {
        int i = oi / OC, col = oi % OC;
        int h_ = col / 32;
        const float* ap = a_s + h_ * 49 + i * 7;
        const float* vp = q_s + 512 + col;
        float acc = 0.f;
        #pragma unroll
        for (int j = 0; j < 7; j++) acc += ap[j] * vp[j * 768];
        ao[((long long)b * PP + i) * OC + col] = __float2bfloat16(acc);
    }
}

extern "C" void kernel_launch(void* const* d_in, const int* in_sizes, int n_in,
                              void* d_out, int out_size, void* d_ws, size_t ws_size,
                              hipStream_t stream) {
    const float* sil   = (const float*)d_in[0];
    const float* pose  = (const float*)d_in[1];
    const float* fcbin = (const float*)d_in[2];
    const float* gamma = (const float*)d_in[3];
    const float* beta  = (const float*)d_in[4];
    const float* wqkv  = (const float*)d_in[5];
    const float* wproj = (const float*)d_in[6];
    const int*   minidx= (const int*)d_in[7];
    float* out = (float*)d_out;

    float* ws = (float*)d_ws;
    float* rowstat = ws;                                        // 1,966,080 f32
    __hip_bfloat16* fuse16   = (__hip_bfloat16*)(ws + 1966080); // 5,160,960 bf16
    float* xraw    = ws + 4546560;                              // 860,160 f32
    float* partial = ws + 5406720;                              // 28,672
    float* ssbuf   = ws + 5435392;                              // 512
    __hip_bfloat16* wqkv16   = (__hip_bfloat16*)(ws + 5435904); // 196,608 bf16
    __hip_bfloat16* wproj16  = (__hip_bfloat16*)(ws + 5534208); // 65,536 bf16
    __hip_bfloat16* fcbinT16 = (__hip_bfloat16*)(ws + 5566976); // 2,752,512 bf16
    float* qkvbuf  = ws + 6943232;                              // 2,580,480
    __hip_bfloat16* ao16     = (__hip_bfloat16*)(ws + 9523712); // 860,160 bf16

    rowpool<<<7680, 256, 0, stream>>>(sil, rowstat);
    weightprep<<<1696, 256, 0, stream>>>(wqkv, wproj, fcbin, wqkv16, wproj16, fcbinT16);
    fusefill<<<20160, 256, 0, stream>>>(rowstat, pose, minidx, fuse16);
    // fc: per-part [480 x 1536] * [1536 x 256]^T-of-NxK, + BN partials
    gemm2<true, 0><<<dim3(8, 4, 7), 256, 0, stream>>>(fuse16, fcbinT16, xraw, nullptr,
        nullptr, partial, nullptr,
        480, 256, 1536, 1536, 1792, (long long)480 * 1536, (long long)256 * 1536, 256);
    bnfinal<<<1, 256, 0, stream>>>(partial, gamma, beta, ssbuf);
    // qkv: BN(xraw) [3360 x 256] * wqkv [768 x 256]^T
    gemm2<false, 1><<<dim3(53, 12, 1), 256, 0, stream>>>(xraw, wqkv16, qkvbuf, nullptr,
        nullptr, nullptr, ssbuf,
        3360, 768, 256, 256, 768, 0, 0, 0);
    attn_core<<<480, 256, 0, stream>>>(qkvbuf, ao16);
    // proj + residual(BN(xraw)) + transposed out
    gemm2<true, 2><<<dim3(53, 4, 1), 256, 0, stream>>>(ao16, wproj16, nullptr, out,
        xraw, nullptr, ssbuf,
        3360, 256, 256, 256, 256, 0, 0, 0);
}

// Round 4
// 83.308 us; speedup vs baseline: 3.6134x; 1.1518x over previous
//
#include <hip/hip_runtime.h>
#include <hip/hip_bf16.h>
#include <math.h>

#define NS 480   // n*s
#define NN 16
#define SS 30
#define CC 64
#define HHH 64
#define WW 22
#define PP 7
#define MAXH 22
#define CP 64
#define VV 17
#define DD 1536
#define OC 256
#define SILD 1408   // c*MAXH
#define NTOK 3360   // NS*PP

typedef __bf16 bf16x8 __attribute__((ext_vector_type(8)));
typedef float f32x4 __attribute__((ext_vector_type(4)));
typedef short short8 __attribute__((ext_vector_type(8)));

__device__ __forceinline__ void gl_lds16(const void* g, void* l) {
    __builtin_amdgcn_global_load_lds(
        (const __attribute__((address_space(1))) void*)g,
        (__attribute__((address_space(3))) void*)l, 16, 0, 0);
}

__device__ __forceinline__ float bf2f(short s) {
    union { float f; unsigned u; } uu; uu.u = ((unsigned)(unsigned short)s) << 16; return uu.f;
}

// ---------------- K1: width pool (mean+max over w=22) + part gather, fused ----------------
// Each block: 5632 consecutive floats of sil = 4 (n,c,s) triples x 64 h x 22 w.
// Pool -> hbuf[4][64], then scatter rows [mi, mi+22) for all 7 parts into fuse (bf16).
__global__ __launch_bounds__(256) void rowfuse(const float* __restrict__ sil,
                                               const int* __restrict__ min_idx,
                                               __hip_bfloat16* __restrict__ fuse) {
    __shared__ float lds[256 * WW];
    __shared__ float hbuf[4][64];
    __shared__ int mi_s[112];
    int tid = threadIdx.x;
    if (tid < 112) mi_s[tid] = min_idx[tid];
    long long base = (long long)blockIdx.x * (256 * WW);
    const float4* src = (const float4*)(sil + base);
    float4* dst4 = (float4*)lds;
    for (int i = tid; i < 256 * WW / 4; i += 256) dst4[i] = src[i];
    __syncthreads();
    const float* row = lds + tid * WW;
    float s = 0.f, m = -INFINITY;
    #pragma unroll
    for (int k = 0; k < WW; k++) { float v = row[k]; s += v; m = fmaxf(m, v); }
    hbuf[tid >> 6][tid & 63] = s * (1.0f / WW) + m;
    __syncthreads();
    int q0 = blockIdx.x * 4;       // q = (n*64 + c)*30 + s
    for (int idx = tid; idx < 4 * PP * MAXH; idx += 256) {
        int qi = idx / (PP * MAXH), r = idx % (PP * MAXH);
        int j = r / MAXH, hh = r % MAXH;
        int q = q0 + qi;
        int s_i = q % SS, t = q / SS;
        int c = t & 63, n = t >> 6;
        int mi = mi_s[j * NN + n];
        float v = hbuf[qi][mi + hh];
        fuse[((long long)(j * NS + n * SS + s_i)) * DD + c * MAXH + hh] = __float2bfloat16(v);
    }
}

// ---------------- weight prep + pose columns of fuse ----------------
__global__ __launch_bounds__(256) void weightprep(const float* __restrict__ wqkv,
                                                  const float* __restrict__ wproj,
                                                  const float* __restrict__ fcbin,
                                                  const float* __restrict__ pose,
                                                  __hip_bfloat16* __restrict__ wqkv16,
                                                  __hip_bfloat16* __restrict__ wproj16,
                                                  __hip_bfloat16* __restrict__ fcbinT16,
                                                  __hip_bfloat16* __restrict__ fuse) {
    int b = blockIdx.x;
    if (b < 768) { int g = b * 256 + threadIdx.x; wqkv16[g] = __float2bfloat16(wqkv[g]); return; }
    if (b < 1024) { int g = (b - 768) * 256 + threadIdx.x; wproj16[g] = __float2bfloat16(wproj[g]); return; }
    if (b < 1696) {
        __shared__ float t[64][65];
        int bb = b - 1024;                 // 0..671
        int p = bb / 96, r2 = bb % 96, dt = r2 / 4, ot = r2 % 4;
        const float* s = fcbin + ((long long)p * DD + dt * 64) * OC + ot * 64;
        for (int i = threadIdx.x; i < 64 * 64; i += 256) {
            int r = i >> 6, c = i & 63;
            t[r][c] = s[(long long)r * OC + c];
        }
        __syncthreads();
        __hip_bfloat16* d = fcbinT16 + ((long long)p * OC + ot * 64) * DD + dt * 64;
        for (int i = threadIdx.x; i < 64 * 64; i += 256) {
            int r = i >> 6, c = i & 63;
            d[(long long)r * DD + c] = __float2bfloat16(t[c][r]);
        }
        return;
    }
    // pose columns: 7*480*128 elements
    int g = (b - 1696) * 256 + threadIdx.x;
    int dd = g & 127;
    int t2 = g >> 7;
    int nsi = t2 % NS;
    int j = t2 / NS;
    int n = nsi / SS, s_i = nsi % SS;
    int cpi = dd >> 1, par = dd & 1;
    const float* pr = pose + (((long long)n * CP + cpi) * SS + s_i) * VV;
    float v;
    if (j == 0) {
        v = (par == 0) ? (pr[0] + pr[1] + pr[2]) * (1.f / 3.f)
                       : (pr[2] + pr[3] + pr[4]) * (1.f / 3.f);
    } else {
        v = pr[5 + (j - 1) * 2 + par];
    }
    v = (v > 0.f) ? v : 0.01f * v;
    fuse[(long long)(j * NS + nsi) * DD + SILD + dd] = __float2bfloat16(v);
}

// ---------------- unified MFMA GEMM, 64x64 tile, 2-phase dbuf, gload_lds ----------------
// ABF16: A bf16 via global_load_lds; else A = f32 with BN applied on stage.
// EPI 0: C=f32 + BN column partials.  EPI 1: C=bf16.
template<bool ABF16, int EPI>
__global__ __launch_bounds__(256) void gemm2(
    const void* __restrict__ Ain, const __hip_bfloat16* __restrict__ Bt,
    float* __restrict__ Cf, __hip_bfloat16* __restrict__ Cb,
    float* __restrict__ partial, const float* __restrict__ ssb,
    int M, int N, int K, int lda, int ldc,
    long long aBatch, long long bBatch, long long cBatch)
{
    const __hip_bfloat16* Ab = (const __hip_bfloat16*)Ain + (ABF16 ? (long long)blockIdx.z * aBatch : 0);
    const float* Af = (const float*)Ain;
    const __hip_bfloat16* Bq = Bt + (long long)blockIdx.z * bBatch;
    float* C = Cf ? (Cf + (long long)blockIdx.z * cBatch) : nullptr;

    __shared__ short As[2][4096];
    __shared__ short Bs[2][4096];
    __shared__ float red[4][2][16][2];
    __shared__ float ssl[512];

    int tid = threadIdx.x, lane = tid & 63, w = tid >> 6;
    int wm = w >> 1, wn = w & 1;
    int row0 = blockIdx.x * 64, col0 = blockIdx.y * 64;

    if (!ABF16) {
        for (int i = tid; i < 512; i += 256) ssl[i] = ssb[i];
        __syncthreads();
    }

    f32x4 acc[2][2] = {};
    int nt = K >> 6;

    auto stageB = [&](int buf, int k0) {
        int cc = lane & 7;
        #pragma unroll
        for (int i = 0; i < 2; i++) {
            int r = w * 16 + i * 8 + (lane >> 3);
            int gcol = col0 + r; if (gcol >= N) gcol = N - 1;
            const char* g = (const char*)Bq + (((long long)gcol * K + k0) << 1) + ((cc ^ (r & 7)) << 4);
            gl_lds16(g, (char*)&Bs[buf][0] + (w * 16 + i * 8) * 128);
        }
    };
    auto stageA = [&](int buf, int k0) {
        if constexpr (ABF16) {
            int cc = lane & 7;
            #pragma unroll
            for (int i = 0; i < 2; i++) {
                int r = w * 16 + i * 8 + (lane >> 3);
                int grow = row0 + r; if (grow >= M) grow = M - 1;
                const char* g = (const char*)Ab + (((long long)grow * lda + k0) << 1) + ((cc ^ (r & 7)) << 4);
                gl_lds16(g, (char*)&As[buf][0] + (w * 16 + i * 8) * 128);
            }
        } else {
            #pragma unroll
            for (int i = 0; i < 2; i++) {
                int id = tid + i * 256;          // 0..511
                int r = id >> 3, c8 = id & 7;
                int grow = row0 + r; if (grow >= M) grow = M - 1;
                const float* src = Af + (long long)grow * lda + k0 + c8 * 8;
                float4 v0 = *(const float4*)src;
                float4 v1 = *(const float4*)(src + 4);
                int kb = k0 + c8 * 8;
                float vv[8] = {v0.x, v0.y, v0.z, v0.w, v1.x, v1.y, v1.z, v1.w};
                short8 o;
                #pragma unroll
                for (int j = 0; j < 8; j++) {
                    float tv = vv[j] * ssl[kb + j] + ssl[256 + kb + j];
                    union { __hip_bfloat16 h; short s; } u; u.h = __float2bfloat16(tv);
                    o[j] = u.s;
                }
                *(short8*)((char*)&As[buf][0] + r * 128 + ((c8 ^ (r & 7)) << 4)) = o;
            }
        }
    };

    stageA(0, 0); stageB(0, 0);
    __syncthreads();
    for (int t = 0; t < nt; t++) {
        int cur = t & 1;
        if (t + 1 < nt) { stageA(cur ^ 1, (t + 1) << 6); stageB(cur ^ 1, (t + 1) << 6); }
        #pragma unroll
        for (int ks = 0; ks < 2; ks++) {
            bf16x8 af[2], bfv[2];
            #pragma unroll
            for (int f = 0; f < 2; f++) {
                int r = wm * 32 + f * 16 + (lane & 15);
                int ca = (ks * 4 + (lane >> 4)) ^ (r & 7);
                af[f] = *(const bf16x8*)((const char*)&As[cur][0] + r * 128 + (ca << 4));
                int rb = wn * 32 + f * 16 + (lane & 15);
                int cb = (ks * 4 + (lane >> 4)) ^ (rb & 7);
                bfv[f] = *(const bf16x8*)((const char*)&Bs[cur][0] + rb * 128 + (cb << 4));
            }
            #pragma unroll
            for (int fm = 0; fm < 2; fm++)
                #pragma unroll
                for (int fn = 0; fn < 2; fn++)
                    acc[fm][fn] = __builtin_amdgcn_mfma_f32_16x16x32_bf16(
                        af[fm], bfv[fn], acc[fm][fn], 0, 0, 0);
        }
        __syncthreads();
    }

    if constexpr (EPI == 0) {
        float s[2] = {0.f, 0.f}, s2[2] = {0.f, 0.f};
        #pragma unroll
        for (int fm = 0; fm < 2; fm++) {
            #pragma unroll
            for (int fn = 0; fn < 2; fn++) {
                #pragma unroll
                for (int r4 = 0; r4 < 4; r4++) {
                    int grow = row0 + wm * 32 + fm * 16 + (lane >> 4) * 4 + r4;
                    int gcol = col0 + wn * 32 + fn * 16 + (lane & 15);
                    if (grow < M) {
                        float v = acc[fm][fn][r4];
                        C[(long long)grow * ldc + gcol] = v;
                        s[fn] += v; s2[fn] += v * v;
                    }
                }
            }
        }
        #pragma unroll
        for (int off = 16; off < 64; off <<= 1) {
            s[0] += __shfl_xor(s[0], off);  s2[0] += __shfl_xor(s2[0], off);
            s[1] += __shfl_xor(s[1], off);  s2[1] += __shfl_xor(s2[1], off);
        }
        if (lane < 16) {
            red[w][0][lane][0] = s[0]; red[w][0][lane][1] = s2[0];
            red[w][1][lane][0] = s[1]; red[w][1][lane][1] = s2[1];
        }
        __syncthreads();
        if (tid < 128) {
            int col = tid >> 1, which = tid & 1;
            int wn2 = (col >> 5) & 1, fn2 = (col >> 4) & 1, c16 = col & 15;
            float v = red[wn2][fn2][c16][which] + red[2 + wn2][fn2][c16][which];
            partial[((long long)(blockIdx.z * 8 + blockIdx.x) * 2 + which) * 256 + blockIdx.y * 64 + col] = v;
        }
    } else {
        #pragma unroll
        for (int fm = 0; fm < 2; fm++)
            #pragma unroll
            for (int fn = 0; fn < 2; fn++)
                #pragma unroll
                for (int r4 = 0; r4 < 4; r4++) {
                    int grow = row0 + wm * 32 + fm * 16 + (lane >> 4) * 4 + r4;
                    int gcol = col0 + wn * 32 + fn * 16 + (lane & 15);
                    if (grow < M) Cb[(long long)grow * ldc + gcol] = __float2bfloat16(acc[fm][fn][r4]);
                }
    }
}

// ---------------- BN final: partials -> scale/shift ----------------
__global__ __launch_bounds__(256) void bnfinal(const float* __restrict__ partial,
                                               const float* __restrict__ gamma,
                                               const float* __restrict__ beta,
                                               float* __restrict__ ssbuf) {
    int t = threadIdx.x;
    float s = 0.f, s2 = 0.f;
    for (int b = 0; b < 56; b++) { s += partial[b * 512 + t]; s2 += partial[b * 512 + 256 + t]; }
    float mu = s / (float)NTOK;
    float var = s2 / (float)NTOK - mu * mu;
    float rsig = rsqrtf(var + 1e-5f);
    float sc = gamma[t] * rsig;
    ssbuf[t] = sc;
    ssbuf[256 + t] = beta[t] - mu * sc;
}

// ---------------- fused attention + proj + residual + transposed out ----------------
// block = 14 tokens (2 attn batches); 240 blocks. qkv16: [3360][768] bf16.
__global__ __launch_bounds__(256) void attnproj(const __hip_bfloat16* __restrict__ qkv16,
                                                const __hip_bfloat16* __restrict__ wproj16,
                                                const float* __restrict__ xraw,
                                                const float* __restrict__ ssb,
                                                float* __restrict__ outp) {
    __shared__ float qs[14 * 768];
    __shared__ float as_[2][8][49];
    __shared__ short ao_s[16 * 256];
    __shared__ float Ct[256 * 17];
    __shared__ float ssl[512];

    int tid = threadIdx.x, lane = tid & 63, w = tid >> 6;
    int token0 = blockIdx.x * 14;

    for (int i = tid; i < 512; i += 256) ssl[i] = ssb[i];

    const short* src = (const short*)qkv16 + (long long)token0 * 768;
    for (int i = tid; i < 14 * 768 / 8; i += 256) {
        short8 v = *(const short8*)(src + i * 8);
        #pragma unroll
        for (int j = 0; j < 8; j++) qs[i * 8 + j] = bf2f(v[j]);
    }
    __syncthreads();
    for (int t = tid; t < 784; t += 256) {
        int bb = t / 392, r = t % 392, h = r / 49, ij = r % 49, i = ij / 7, j = ij % 7;
        const float* qp = qs + (bb * 7 + i) * 768 + h * 32;
        const float* kp = qs + (bb * 7 + j) * 768 + 256 + h * 32;
        float acc = 0.f;
        #pragma unroll
        for (int d = 0; d < 32; d++) acc += qp[d] * kp[d];
        as_[bb][h][ij] = acc * 0.17677669529663689f;
    }
    __syncthreads();
    if (tid < 98) {
        int bb = tid / 49, ij = tid % 49;
        float m = -INFINITY;
        #pragma unroll
        for (int h = 0; h < 8; h++) m = fmaxf(m, as_[bb][h][ij]);
        float e[8], sum = 0.f;
        #pragma unroll
        for (int h = 0; h < 8; h++) { e[h] = __expf(as_[bb][h][ij] - m); sum += e[h]; }
        float inv = 1.f / sum;
        #pragma unroll
        for (int h = 0; h < 8; h++) as_[bb][h][ij] = e[h] * inv;
    }
    __syncthreads();
    // ao rows (pad 14,15 with zeros), XOR-swizzled bf16 store for MFMA A-frag reads
    for (int t = tid; t < 16 * 256; t += 256) {
        int tl = t >> 8, col = t & 255;
        float acc = 0.f;
        if (tl < 14) {
            int bb = tl / 7, i = tl % 7, h = col >> 5;
            const float* ap = &as_[bb][h][i * 7];
            const float* vp = qs + (bb * 7) * 768 + 512 + col;
            #pragma unroll
            for (int j = 0; j < 7; j++) acc += ap[j] * vp[j * 768];
        }
        int c16 = col >> 3;
        union { __hip_bfloat16 h2; short s2; } u; u.h2 = __float2bfloat16(acc);
        ao_s[tl * 256 + ((c16 ^ (tl & 7)) << 3) + (col & 7)] = u.s2;
    }
    __syncthreads();
    // proj MFMA: wave w -> n0 = w*64; A from ao_s, B direct from L2 (wproj16 [N][K])
    f32x4 pacc[4] = {};
    int n0 = w * 64;
    #pragma unroll
    for (int k0 = 0; k0 < 256; k0 += 32) {
        int rowa = lane & 15;
        int kk = k0 + (lane >> 4) * 8;
        int c16a = kk >> 3;
        bf16x8 af = *(const bf16x8*)(const void*)&ao_s[rowa * 256 + ((c16a ^ (rowa & 7)) << 3)];
        #pragma unroll
        for (int fn = 0; fn < 4; fn++) {
            int n = n0 + fn * 16 + (lane & 15);
            bf16x8 bfv = *(const bf16x8*)(const void*)((const short*)wproj16 + n * 256 + kk);
            pacc[fn] = __builtin_amdgcn_mfma_f32_16x16x32_bf16(af, bfv, pacc[fn], 0, 0, 0);
        }
    }
    #pragma unroll
    for (int fn = 0; fn < 4; fn++)
        #pragma unroll
        for (int r4 = 0; r4 < 4; r4++) {
            int o = n0 + fn * 16 + (lane & 15);
            int t = (lane >> 4) * 4 + r4;
            Ct[o * 17 + t] = pacc[fn][r4];
        }
    __syncthreads();
    // residual(BN(xraw)) + transposed write: thread = output channel o
    int o = tid;
    int n = token0 / 210, rem0 = token0 % 210;
    float* op = outp + ((long long)(n * 256 + o)) * 210 + rem0;
    float sc = ssl[o], sh = ssl[256 + o];
    #pragma unroll
    for (int t2 = 0; t2 < 14; t2 += 2) {
        float2 v;
        v.x = Ct[o * 17 + t2]     + xraw[(long long)(token0 + t2) * 256 + o] * sc + sh;
        v.y = Ct[o * 17 + t2 + 1] + xraw[(long long)(token0 + t2 + 1) * 256 + o] * sc + sh;
        *(float2*)(op + t2) = v;
    }
}

extern "C" void kernel_launch(void* const* d_in, const int* in_sizes, int n_in,
                              void* d_out, int out_size, void* d_ws, size_t ws_size,
                              hipStream_t stream) {
    const float* sil   = (const float*)d_in[0];
    const float* pose  = (const float*)d_in[1];
    const float* fcbin = (const float*)d_in[2];
    const float* gamma = (const float*)d_in[3];
    const float* beta  = (const float*)d_in[4];
    const float* wqkv  = (const float*)d_in[5];
    const float* wproj = (const float*)d_in[6];
    const int*   minidx= (const int*)d_in[7];
    float* out = (float*)d_out;

    float* ws = (float*)d_ws;
    __hip_bfloat16* fuse16   = (__hip_bfloat16*)ws;             // 5,160,960 bf16 -> 2,580,480 f32
    float* xraw    = ws + 2580480;                              // 860,160 f32
    float* partial = ws + 3440640;                              // 28,672
    float* ssbuf   = ws + 3469312;                              // 512
    __hip_bfloat16* wqkv16   = (__hip_bfloat16*)(ws + 3469824); // 196,608 bf16
    __hip_bfloat16* wproj16  = (__hip_bfloat16*)(ws + 3568128); // 65,536 bf16
    __hip_bfloat16* fcbinT16 = (__hip_bfloat16*)(ws + 3600896); // 2,752,512 bf16
    __hip_bfloat16* qkv16    = (__hip_bfloat16*)(ws + 4977152); // 2,580,480 bf16

    rowfuse<<<7680, 256, 0, stream>>>(sil, minidx, fuse16);
    weightprep<<<3376, 256, 0, stream>>>(wqkv, wproj, fcbin, pose,
                                         wqkv16, wproj16, fcbinT16, fuse16);
    // fc: per-part [480 x 1536] * fcbinT [256 x 1536]^T, writes xraw + BN partials
    gemm2<true, 0><<<dim3(8, 4, 7), 256, 0, stream>>>(fuse16, fcbinT16, xraw, nullptr,
        partial, nullptr,
        480, 256, 1536, 1536, 1792, (long long)480 * 1536, (long long)256 * 1536, 256);
    bnfinal<<<1, 256, 0, stream>>>(partial, gamma, beta, ssbuf);
    // qkv: BN(xraw) [3360 x 256] * wqkv [768 x 256]^T -> bf16
    gemm2<false, 1><<<dim3(53, 12, 1), 256, 0, stream>>>(xraw, wqkv16, nullptr, qkv16,
        nullptr, ssbuf,
        3360, 768, 256, 256, 768, 0, 0, 0);
    attnproj<<<240, 256, 0, stream>>>(qkv16, wproj16, xraw, ssbuf, out);
}